// Round 5
// baseline (351.018 us; speedup 1.0000x reference)
//
#include <hip/hip_runtime.h>

#define NN 50000
#define NE 1600000
#define BSTRIDE 96   // max degree slots; Poisson(32) tail at 96 is ~e^-41 per node
#define PARTN 6250   // NN / 8 XCDs
#define FILL_GRPS 512
#define FILL_CHUNK 3125  // NE / FILL_GRPS exactly

// ---------- bf16 helpers (RNE) ----------
__device__ __forceinline__ float bfLo(uint u) { union { uint i; float f; } v; v.i = u << 16; return v.f; }
__device__ __forceinline__ float bfHi(uint u) { union { uint i; float f; } v; v.i = u & 0xffff0000u; return v.f; }
__device__ __forceinline__ ushort f2bf(float f) {
    union { float f; uint i; } v; v.f = f;
    uint r = v.i + 0x7fffu + ((v.i >> 16) & 1u);
    return (ushort)(r >> 16);
}
__device__ __forceinline__ uint pack2(float a, float b) {
    return (uint)f2bf(a) | ((uint)f2bf(b) << 16);
}

// ---------- x (fp32) -> bf16 ----------
__global__ void k_cvt(const float4* __restrict__ x, ushort4* __restrict__ xb) {
    int i = blockIdx.x * 256 + threadIdx.x;   // exactly NN*128/4 = 1.6M threads
    float4 v = x[i];
    ushort4 o; o.x = f2bf(v.x); o.y = f2bf(v.y); o.z = f2bf(v.z); o.w = f2bf(v.w);
    xb[i] = o;
}

// ---------- bucketed CSR fill, XCD-partitioned by dst range ----------
// dst/src reads are single-use streams per XCD -> non-temporal (evict-first in
// L2) so the XCD's 1.2 MB dirty col slice stays resident -> 1 writeback/line.
__global__ __launch_bounds__(256) void k_fill(const int* __restrict__ src, const int* __restrict__ dst,
                       int* __restrict__ cursor, ushort* __restrict__ col) {
    const int xcd = blockIdx.x & 7;
    const int grp = blockIdx.x >> 3;           // 0..FILL_GRPS-1
    const int lo = xcd * PARTN;
    const int beg = grp * FILL_CHUNK;
    const int end = beg + FILL_CHUNK;
    #pragma unroll 8
    for (int i = beg + threadIdx.x; i < end; i += 256) {
        int d = __builtin_nontemporal_load(&dst[i]);
        if ((unsigned)(d - lo) < (unsigned)PARTN) {
            int s = __builtin_nontemporal_load(&src[i]);
            int p = atomicAdd(&cursor[d], 1);
            if (p < BSTRIDE) col[(size_t)d * BSTRIDE + p] = (ushort)s;
        }
    }
}

// ---------- aggregation, 128-dim bf16 rows ----------
// one wave per node; quarter-wave (16 lanes x 16B) covers one 256B neighbor row
// -> one wave-load serves 4 neighbors. 8 fp32 accumulators per lane.
__global__ void k_agg128(const ushort* __restrict__ feat, const ushort* __restrict__ col,
                         const int* __restrict__ deg, ushort* __restrict__ out) {
    int node = (blockIdx.x * blockDim.x + threadIdx.x) >> 6;
    int lane = threadIdx.x & 63;
    int q = lane >> 4;         // neighbor slot within group of 4
    int c = lane & 15;         // dim group: dims c*8 .. c*8+7
    int d = deg[node];
    int dd = min(d, BSTRIDE);
    const ushort* cb = col + (size_t)node * BSTRIDE;
    float a0=0.f,a1=0.f,a2=0.f,a3=0.f,a4=0.f,a5=0.f,a6=0.f,a7=0.f;
    for (int j0 = 0; j0 < dd; j0 += 64) {
        int idx = (j0 + lane < dd) ? (int)cb[j0 + lane] : 0;
        int cnt = min(64, dd - j0);
        for (int t = 0; t < cnt; t += 4) {
            int s = __shfl(idx, t + q);
            if (t + q < cnt) {
                uint4 u = *(const uint4*)(feat + (size_t)s * 128 + c * 8);
                a0 += bfLo(u.x); a1 += bfHi(u.x);
                a2 += bfLo(u.y); a3 += bfHi(u.y);
                a4 += bfLo(u.z); a5 += bfHi(u.z);
                a6 += bfLo(u.w); a7 += bfHi(u.w);
            }
        }
    }
    a0 += __shfl_xor(a0, 16); a0 += __shfl_xor(a0, 32);
    a1 += __shfl_xor(a1, 16); a1 += __shfl_xor(a1, 32);
    a2 += __shfl_xor(a2, 16); a2 += __shfl_xor(a2, 32);
    a3 += __shfl_xor(a3, 16); a3 += __shfl_xor(a3, 32);
    a4 += __shfl_xor(a4, 16); a4 += __shfl_xor(a4, 32);
    a5 += __shfl_xor(a5, 16); a5 += __shfl_xor(a5, 32);
    a6 += __shfl_xor(a6, 16); a6 += __shfl_xor(a6, 32);
    a7 += __shfl_xor(a7, 16); a7 += __shfl_xor(a7, 32);
    if (q == 0) {
        float inv = 1.f / fmaxf((float)d, 1.f);
        uint4 o;
        o.x = pack2(a0 * inv, a1 * inv);
        o.y = pack2(a2 * inv, a3 * inv);
        o.z = pack2(a4 * inv, a5 * inv);
        o.w = pack2(a6 * inv, a7 * inv);
        *(uint4*)(out + (size_t)node * 128 + c * 8) = o;
    }
}

// ---------- aggregation, 64-dim bf16 rows ----------
// one wave per node; 8 lanes x 16B cover one 128B row -> 8 neighbors per wave-load.
__global__ void k_agg64(const ushort* __restrict__ feat, const ushort* __restrict__ col,
                        const int* __restrict__ deg, ushort* __restrict__ out) {
    int node = (blockIdx.x * blockDim.x + threadIdx.x) >> 6;
    int lane = threadIdx.x & 63;
    int q = lane >> 3;         // neighbor slot within group of 8
    int c = lane & 7;          // dim group: dims c*8 .. c*8+7
    int d = deg[node];
    int dd = min(d, BSTRIDE);
    const ushort* cb = col + (size_t)node * BSTRIDE;
    float a0=0.f,a1=0.f,a2=0.f,a3=0.f,a4=0.f,a5=0.f,a6=0.f,a7=0.f;
    for (int j0 = 0; j0 < dd; j0 += 64) {
        int idx = (j0 + lane < dd) ? (int)cb[j0 + lane] : 0;
        int cnt = min(64, dd - j0);
        for (int t = 0; t < cnt; t += 8) {
            int s = __shfl(idx, t + q);
            if (t + q < cnt) {
                uint4 u = *(const uint4*)(feat + (size_t)s * 64 + c * 8);
                a0 += bfLo(u.x); a1 += bfHi(u.x);
                a2 += bfLo(u.y); a3 += bfHi(u.y);
                a4 += bfLo(u.z); a5 += bfHi(u.z);
                a6 += bfLo(u.w); a7 += bfHi(u.w);
            }
        }
    }
    #pragma unroll
    for (int m = 8; m < 64; m <<= 1) {
        a0 += __shfl_xor(a0, m); a1 += __shfl_xor(a1, m);
        a2 += __shfl_xor(a2, m); a3 += __shfl_xor(a3, m);
        a4 += __shfl_xor(a4, m); a5 += __shfl_xor(a5, m);
        a6 += __shfl_xor(a6, m); a7 += __shfl_xor(a7, m);
    }
    if (q == 0) {
        float inv = 1.f / fmaxf((float)d, 1.f);
        uint4 o;
        o.x = pack2(a0 * inv, a1 * inv);
        o.y = pack2(a2 * inv, a3 * inv);
        o.z = pack2(a4 * inv, a5 * inv);
        o.w = pack2(a6 * inv, a7 * inv);
        *(uint4*)(out + (size_t)node * 64 + c * 8) = o;
    }
}

// ---------- GEMM 1: h = relu(agg1@W1_l + x@W1_r + b1)  [bf16 A, fp32 W, bf16 out] ----------
// block: 64 rows x 128 cols, 256 threads, 4x8 per thread
__global__ __launch_bounds__(256) void k_gemm1(
    const ushort* __restrict__ agg, const ushort* __restrict__ xb,
    const float* __restrict__ Wl, const float* __restrict__ Wr,
    const float* __restrict__ bias, ushort* __restrict__ out) {
    __shared__ float As[64 * 33];
    __shared__ float Bs[32 * 132];
    const int tid = threadIdx.x;
    const int tx = tid & 15;
    const int ty = tid >> 4;
    const int rowBase = blockIdx.x * 64;
    float acc[4][8];
    #pragma unroll
    for (int i = 0; i < 4; i++)
        #pragma unroll
        for (int j = 0; j < 8; j++) acc[i][j] = 0.f;

    for (int seg = 0; seg < 2; seg++) {
        const ushort* A = seg ? xb : agg;
        const float* W = seg ? Wr : Wl;
        for (int kt = 0; kt < 4; kt++) {
            {
                int row = tid >> 2;
                int ko = (tid & 3) * 8;
                int gr = min(rowBase + row, NN - 1);
                uint4 v = *(const uint4*)(A + (size_t)gr * 128 + kt * 32 + ko);
                float* dp = &As[row * 33 + ko];
                dp[0] = bfLo(v.x); dp[1] = bfHi(v.x);
                dp[2] = bfLo(v.y); dp[3] = bfHi(v.y);
                dp[4] = bfLo(v.z); dp[5] = bfHi(v.z);
                dp[6] = bfLo(v.w); dp[7] = bfHi(v.w);
            }
            #pragma unroll
            for (int p = 0; p < 4; p++) {
                int idx = p * 256 + tid;
                int kk = idx >> 5;
                int c4 = idx & 31;
                float4 v = *(const float4*)(W + (size_t)(kt * 32 + kk) * 128 + c4 * 4);
                *(float4*)&Bs[kk * 132 + c4 * 4] = v;
            }
            __syncthreads();
            #pragma unroll
            for (int kk = 0; kk < 32; kk++) {
                float a[4];
                #pragma unroll
                for (int i = 0; i < 4; i++) a[i] = As[(ty * 4 + i) * 33 + kk];
                float4 bl = *(const float4*)&Bs[kk * 132 + tx * 4];
                float4 bh = *(const float4*)&Bs[kk * 132 + 64 + tx * 4];
                #pragma unroll
                for (int i = 0; i < 4; i++) {
                    acc[i][0] += a[i] * bl.x; acc[i][1] += a[i] * bl.y;
                    acc[i][2] += a[i] * bl.z; acc[i][3] += a[i] * bl.w;
                    acc[i][4] += a[i] * bh.x; acc[i][5] += a[i] * bh.y;
                    acc[i][6] += a[i] * bh.z; acc[i][7] += a[i] * bh.w;
                }
            }
            __syncthreads();
        }
    }
    const float4 b_lo = *(const float4*)(bias + tx * 4);
    const float4 b_hi = *(const float4*)(bias + 64 + tx * 4);
    #pragma unroll
    for (int i = 0; i < 4; i++) {
        int r = rowBase + ty * 4 + i;
        if (r < NN) {
            uint2 o;
            o.x = pack2(fmaxf(acc[i][0] + b_lo.x, 0.f), fmaxf(acc[i][1] + b_lo.y, 0.f));
            o.y = pack2(fmaxf(acc[i][2] + b_lo.z, 0.f), fmaxf(acc[i][3] + b_lo.w, 0.f));
            *(uint2*)(out + (size_t)r * 128 + tx * 4) = o;
            o.x = pack2(fmaxf(acc[i][4] + b_hi.x, 0.f), fmaxf(acc[i][5] + b_hi.y, 0.f));
            o.y = pack2(fmaxf(acc[i][6] + b_hi.z, 0.f), fmaxf(acc[i][7] + b_hi.w, 0.f));
            *(uint2*)(out + (size_t)r * 128 + 64 + tx * 4) = o;
        }
    }
}

// ---------- GEMM 2: [N,128]bf16 @ [128,64]fp32 ; MODE 0 -> bf16 store, MODE 1 -> +agg2+bias fp32 store ----------
template <int MODE>
__global__ __launch_bounds__(256) void k_gemm2(
    const ushort* __restrict__ A, const float* __restrict__ W,
    const ushort* __restrict__ addend, const float* __restrict__ bias,
    void* __restrict__ outv) {
    __shared__ float As[128 * 33];
    __shared__ float Bs[32 * 68];
    const int tid = threadIdx.x;
    const int tx = tid & 15;
    const int ty = tid >> 4;
    const int rowBase = blockIdx.x * 128;
    float acc[8][4];
    #pragma unroll
    for (int i = 0; i < 8; i++)
        #pragma unroll
        for (int j = 0; j < 4; j++) acc[i][j] = 0.f;

    for (int kt = 0; kt < 4; kt++) {
        #pragma unroll
        for (int p = 0; p < 2; p++) {
            int idx = p * 256 + tid;
            int row = idx >> 2;
            int ko = (idx & 3) * 8;
            int gr = min(rowBase + row, NN - 1);
            uint4 v = *(const uint4*)(A + (size_t)gr * 128 + kt * 32 + ko);
            float* dp = &As[row * 33 + ko];
            dp[0] = bfLo(v.x); dp[1] = bfHi(v.x);
            dp[2] = bfLo(v.y); dp[3] = bfHi(v.y);
            dp[4] = bfLo(v.z); dp[5] = bfHi(v.z);
            dp[6] = bfLo(v.w); dp[7] = bfHi(v.w);
        }
        #pragma unroll
        for (int p = 0; p < 2; p++) {
            int idx = p * 256 + tid;
            int kk = idx >> 4;
            int c4 = idx & 15;
            float4 v = *(const float4*)(W + (size_t)(kt * 32 + kk) * 64 + c4 * 4);
            *(float4*)&Bs[kk * 68 + c4 * 4] = v;
        }
        __syncthreads();
        #pragma unroll
        for (int kk = 0; kk < 32; kk++) {
            float4 bv = *(const float4*)&Bs[kk * 68 + tx * 4];
            #pragma unroll
            for (int i = 0; i < 8; i++) {
                float a = As[(ty * 8 + i) * 33 + kk];
                acc[i][0] += a * bv.x; acc[i][1] += a * bv.y;
                acc[i][2] += a * bv.z; acc[i][3] += a * bv.w;
            }
        }
        __syncthreads();
    }
    #pragma unroll
    for (int i = 0; i < 8; i++) {
        int r = rowBase + ty * 8 + i;
        if (r < NN) {
            if (MODE == 0) {
                ushort* out = (ushort*)outv;
                uint2 o;
                o.x = pack2(acc[i][0], acc[i][1]);
                o.y = pack2(acc[i][2], acc[i][3]);
                *(uint2*)(out + (size_t)r * 64 + tx * 4) = o;
            } else {
                float* out = (float*)outv;
                uint2 ad = *(const uint2*)(addend + (size_t)r * 64 + tx * 4);
                float4 bb = *(const float4*)(bias + tx * 4);
                float4 o;
                o.x = acc[i][0] + bfLo(ad.x) + bb.x;
                o.y = acc[i][1] + bfHi(ad.x) + bb.y;
                o.z = acc[i][2] + bfLo(ad.y) + bb.z;
                o.w = acc[i][3] + bfHi(ad.y) + bb.w;
                *(float4*)(out + (size_t)r * 64 + tx * 4) = o;
            }
        }
    }
}

// ---------- launch ----------
extern "C" void kernel_launch(void* const* d_in, const int* in_sizes, int n_in,
                              void* d_out, int out_size, void* d_ws, size_t ws_size,
                              hipStream_t stream) {
    const float* x   = (const float*)d_in[0];
    const int*   ei  = (const int*)d_in[1];
    const float* W1l = (const float*)d_in[2];
    const float* W1r = (const float*)d_in[3];
    const float* b1  = (const float*)d_in[4];
    const float* W2l = (const float*)d_in[5];
    const float* W2r = (const float*)d_in[6];
    const float* b2  = (const float*)d_in[7];
    float* out = (float*)d_out;

    const int* src = ei;
    const int* dst = ei + NE;

    char* w = (char*)d_ws;
    ushort* col  = (ushort*)w;                   w += (size_t)NN * BSTRIDE * 2;  // 9.6 MB
    int* cursor  = (int*)w;                      w += (size_t)NN * 4;            // 0.2 MB
    ushort* xb   = (ushort*)w;                   w += (size_t)NN * 128 * 2;      // 12.8 MB
    ushort* agg1 = (ushort*)w;                   w += (size_t)NN * 128 * 2;      // 12.8 MB
    ushort* h    = (ushort*)w;                   w += (size_t)NN * 128 * 2;      // 12.8 MB
    ushort* hW   = xb;                           // xb dead after k_agg128/gemm1
    ushort* agg2 = xb + (size_t)NN * 64;

    hipMemsetAsync(cursor, 0, (size_t)NN * 4, stream);
    k_cvt<<<NN * 128 / 4 / 256, 256, 0, stream>>>((const float4*)x, (ushort4*)xb);
    k_fill<<<FILL_GRPS * 8, 256, 0, stream>>>(src, dst, cursor, col);

    k_agg128<<<NN / 4, 256, 0, stream>>>(xb, col, cursor, agg1);
    k_gemm1<<<(NN + 63) / 64, 256, 0, stream>>>(agg1, xb, W1l, W1r, b1, h);

    k_gemm2<0><<<(NN + 127) / 128, 256, 0, stream>>>(h, W2l, nullptr, nullptr, hW);
    k_agg64<<<NN / 4, 256, 0, stream>>>(hW, col, cursor, agg2);
    k_gemm2<1><<<(NN + 127) / 128, 256, 0, stream>>>(h, W2r, agg2, b2, out);
}

// Round 6
// 329.415 us; speedup vs baseline: 1.0656x; 1.0656x over previous
//
#include <hip/hip_runtime.h>

#define NN 50000
#define NE 1600000
#define BSTRIDE 96   // max degree slots; Poisson(32) tail at 96 is ~e^-41 per node
#define PARTN 6250   // NN / 8 XCDs
#define FILL_GRPS 512
#define FILL_CHUNK 3125  // NE / FILL_GRPS exactly

typedef __bf16 bf16x8 __attribute__((ext_vector_type(8)));
typedef float  f32x4  __attribute__((ext_vector_type(4)));

// ---------- bf16 helpers (RNE) ----------
__device__ __forceinline__ float bfLo(uint u) { union { uint i; float f; } v; v.i = u << 16; return v.f; }
__device__ __forceinline__ float bfHi(uint u) { union { uint i; float f; } v; v.i = u & 0xffff0000u; return v.f; }
__device__ __forceinline__ ushort f2bf(float f) {
    union { float f; uint i; } v; v.f = f;
    uint r = v.i + 0x7fffu + ((v.i >> 16) & 1u);
    return (ushort)(r >> 16);
}
__device__ __forceinline__ uint pack2(float a, float b) {
    return (uint)f2bf(a) | ((uint)f2bf(b) << 16);
}
__device__ __forceinline__ bf16x8 load8(const ushort* p) {
    union { uint4 u; bf16x8 b; } v; v.u = *(const uint4*)p; return v.b;
}

// ---------- x (fp32) -> bf16 ----------
__global__ void k_cvt(const float4* __restrict__ x, ushort4* __restrict__ xb) {
    int i = blockIdx.x * 256 + threadIdx.x;   // exactly NN*128/4 = 1.6M threads
    float4 v = x[i];
    ushort4 o; o.x = f2bf(v.x); o.y = f2bf(v.y); o.z = f2bf(v.z); o.w = f2bf(v.w);
    xb[i] = o;
}

// ---------- weights: fp32 [K][N] -> bf16 transposed [N][K], all four in one launch ----------
__global__ void k_cvtW(const float* __restrict__ W1l, const float* __restrict__ W1r,
                       const float* __restrict__ W2l, const float* __restrict__ W2r,
                       ushort* __restrict__ T1l, ushort* __restrict__ T1r,
                       ushort* __restrict__ T2l, ushort* __restrict__ T2r) {
    int i = blockIdx.x * 256 + threadIdx.x;           // 0 .. 49151
    if (i < 16384) {
        int k = i >> 7, n = i & 127; T1l[n * 128 + k] = f2bf(W1l[i]);
    } else if (i < 32768) {
        int j = i - 16384; int k = j >> 7, n = j & 127; T1r[n * 128 + k] = f2bf(W1r[j]);
    } else if (i < 40960) {
        int j = i - 32768; int k = j >> 6, n = j & 63;  T2l[n * 128 + k] = f2bf(W2l[j]);
    } else if (i < 49152) {
        int j = i - 40960; int k = j >> 6, n = j & 63;  T2r[n * 128 + k] = f2bf(W2r[j]);
    }
}

// ---------- bucketed CSR fill, XCD-partitioned by dst range (R3 config) ----------
__global__ __launch_bounds__(256) void k_fill(const int* __restrict__ src, const int* __restrict__ dst,
                       int* __restrict__ cursor, ushort* __restrict__ col) {
    const int xcd = blockIdx.x & 7;
    const int grp = blockIdx.x >> 3;           // 0..FILL_GRPS-1
    const int lo = xcd * PARTN;
    const int beg = grp * FILL_CHUNK;
    const int end = beg + FILL_CHUNK;
    #pragma unroll 4
    for (int i = beg + threadIdx.x; i < end; i += 256) {
        int d = dst[i];
        if ((unsigned)(d - lo) < (unsigned)PARTN) {
            int p = atomicAdd(&cursor[d], 1);
            if (p < BSTRIDE) col[(size_t)d * BSTRIDE + p] = (ushort)src[i];
        }
    }
}

// ---------- aggregation, 128-dim bf16 rows ----------
__global__ void k_agg128(const ushort* __restrict__ feat, const ushort* __restrict__ col,
                         const int* __restrict__ deg, ushort* __restrict__ out) {
    int node = (blockIdx.x * blockDim.x + threadIdx.x) >> 6;
    int lane = threadIdx.x & 63;
    int q = lane >> 4;         // neighbor slot within group of 4
    int c = lane & 15;         // dim group: dims c*8 .. c*8+7
    int d = deg[node];
    int dd = min(d, BSTRIDE);
    const ushort* cb = col + (size_t)node * BSTRIDE;
    float a0=0.f,a1=0.f,a2=0.f,a3=0.f,a4=0.f,a5=0.f,a6=0.f,a7=0.f;
    for (int j0 = 0; j0 < dd; j0 += 64) {
        int idx = (j0 + lane < dd) ? (int)cb[j0 + lane] : 0;
        int cnt = min(64, dd - j0);
        for (int t = 0; t < cnt; t += 4) {
            int s = __shfl(idx, t + q);
            if (t + q < cnt) {
                uint4 u = *(const uint4*)(feat + (size_t)s * 128 + c * 8);
                a0 += bfLo(u.x); a1 += bfHi(u.x);
                a2 += bfLo(u.y); a3 += bfHi(u.y);
                a4 += bfLo(u.z); a5 += bfHi(u.z);
                a6 += bfLo(u.w); a7 += bfHi(u.w);
            }
        }
    }
    a0 += __shfl_xor(a0, 16); a0 += __shfl_xor(a0, 32);
    a1 += __shfl_xor(a1, 16); a1 += __shfl_xor(a1, 32);
    a2 += __shfl_xor(a2, 16); a2 += __shfl_xor(a2, 32);
    a3 += __shfl_xor(a3, 16); a3 += __shfl_xor(a3, 32);
    a4 += __shfl_xor(a4, 16); a4 += __shfl_xor(a4, 32);
    a5 += __shfl_xor(a5, 16); a5 += __shfl_xor(a5, 32);
    a6 += __shfl_xor(a6, 16); a6 += __shfl_xor(a6, 32);
    a7 += __shfl_xor(a7, 16); a7 += __shfl_xor(a7, 32);
    if (q == 0) {
        float inv = 1.f / fmaxf((float)d, 1.f);
        uint4 o;
        o.x = pack2(a0 * inv, a1 * inv);
        o.y = pack2(a2 * inv, a3 * inv);
        o.z = pack2(a4 * inv, a5 * inv);
        o.w = pack2(a6 * inv, a7 * inv);
        *(uint4*)(out + (size_t)node * 128 + c * 8) = o;
    }
}

// ---------- aggregation, 64-dim bf16 rows ----------
__global__ void k_agg64(const ushort* __restrict__ feat, const ushort* __restrict__ col,
                        const int* __restrict__ deg, ushort* __restrict__ out) {
    int node = (blockIdx.x * blockDim.x + threadIdx.x) >> 6;
    int lane = threadIdx.x & 63;
    int q = lane >> 3;         // neighbor slot within group of 8
    int c = lane & 7;          // dim group: dims c*8 .. c*8+7
    int d = deg[node];
    int dd = min(d, BSTRIDE);
    const ushort* cb = col + (size_t)node * BSTRIDE;
    float a0=0.f,a1=0.f,a2=0.f,a3=0.f,a4=0.f,a5=0.f,a6=0.f,a7=0.f;
    for (int j0 = 0; j0 < dd; j0 += 64) {
        int idx = (j0 + lane < dd) ? (int)cb[j0 + lane] : 0;
        int cnt = min(64, dd - j0);
        for (int t = 0; t < cnt; t += 8) {
            int s = __shfl(idx, t + q);
            if (t + q < cnt) {
                uint4 u = *(const uint4*)(feat + (size_t)s * 64 + c * 8);
                a0 += bfLo(u.x); a1 += bfHi(u.x);
                a2 += bfLo(u.y); a3 += bfHi(u.y);
                a4 += bfLo(u.z); a5 += bfHi(u.z);
                a6 += bfLo(u.w); a7 += bfHi(u.w);
            }
        }
    }
    #pragma unroll
    for (int m = 8; m < 64; m <<= 1) {
        a0 += __shfl_xor(a0, m); a1 += __shfl_xor(a1, m);
        a2 += __shfl_xor(a2, m); a3 += __shfl_xor(a3, m);
        a4 += __shfl_xor(a4, m); a5 += __shfl_xor(a5, m);
        a6 += __shfl_xor(a6, m); a7 += __shfl_xor(a7, m);
    }
    if (q == 0) {
        float inv = 1.f / fmaxf((float)d, 1.f);
        uint4 o;
        o.x = pack2(a0 * inv, a1 * inv);
        o.y = pack2(a2 * inv, a3 * inv);
        o.z = pack2(a4 * inv, a5 * inv);
        o.w = pack2(a6 * inv, a7 * inv);
        *(uint4*)(out + (size_t)node * 64 + c * 8) = o;
    }
}

// ---------- MFMA GEMM 1: h = relu(agg1@W1l + xb@W1r + b1) ----------
// 4 waves/block, one 16-row strip per wave, N=128 (8 tiles), K=2x128.
// A-frag: A[m=lane&15][k=quad*8+j] straight from global (rows L1-resident).
// B-frag: WT[n][k] bf16 (n=lane&15 within tile), L1/L2-hot, shared by all blocks.
// C/D: col=lane&15, row=quad*4+reg (m89-verified).
__global__ __launch_bounds__(256) void k_gemm1(
    const ushort* __restrict__ agg, const ushort* __restrict__ xb,
    const ushort* __restrict__ T1l, const ushort* __restrict__ T1r,
    const float* __restrict__ bias, ushort* __restrict__ out) {
    const int lane = threadIdx.x & 63;
    const int quad = lane >> 4, r16 = lane & 15;
    const int row0 = blockIdx.x * 64 + (threadIdx.x >> 6) * 16;
    const int arow = min(row0 + r16, NN - 1);
    f32x4 acc[8];
    #pragma unroll
    for (int nt = 0; nt < 8; nt++) acc[nt] = (f32x4){0.f, 0.f, 0.f, 0.f};

    #pragma unroll
    for (int seg = 0; seg < 2; seg++) {
        const ushort* A  = seg ? xb  : agg;
        const ushort* WT = seg ? T1r : T1l;
        #pragma unroll
        for (int kt = 0; kt < 4; kt++) {
            const int k = kt * 32 + quad * 8;
            bf16x8 af = load8(A + (size_t)arow * 128 + k);
            #pragma unroll
            for (int nt = 0; nt < 8; nt++) {
                bf16x8 bfr = load8(WT + (nt * 16 + r16) * 128 + k);
                acc[nt] = __builtin_amdgcn_mfma_f32_16x16x32_bf16(af, bfr, acc[nt], 0, 0, 0);
            }
        }
    }
    #pragma unroll
    for (int nt = 0; nt < 8; nt++) {
        int c = nt * 16 + r16;
        float bv = bias[c];
        #pragma unroll
        for (int i = 0; i < 4; i++) {
            int rr = row0 + quad * 4 + i;
            if (rr < NN) out[(size_t)rr * 128 + c] = f2bf(fmaxf(acc[nt][i] + bv, 0.f));
        }
    }
}

// ---------- MFMA GEMM 2: A[N,128]bf16 @ WT[64][128] ; MODE 0 -> bf16, MODE 1 -> +agg2+bias fp32 ----------
template <int MODE>
__global__ __launch_bounds__(256) void k_gemm2(
    const ushort* __restrict__ A, const ushort* __restrict__ WT,
    const ushort* __restrict__ addend, const float* __restrict__ bias,
    void* __restrict__ outv) {
    const int lane = threadIdx.x & 63;
    const int quad = lane >> 4, r16 = lane & 15;
    const int row0 = blockIdx.x * 64 + (threadIdx.x >> 6) * 16;
    const int arow = min(row0 + r16, NN - 1);
    f32x4 acc[4];
    #pragma unroll
    for (int nt = 0; nt < 4; nt++) acc[nt] = (f32x4){0.f, 0.f, 0.f, 0.f};

    #pragma unroll
    for (int kt = 0; kt < 4; kt++) {
        const int k = kt * 32 + quad * 8;
        bf16x8 af = load8(A + (size_t)arow * 128 + k);
        #pragma unroll
        for (int nt = 0; nt < 4; nt++) {
            bf16x8 bfr = load8(WT + (nt * 16 + r16) * 128 + k);
            acc[nt] = __builtin_amdgcn_mfma_f32_16x16x32_bf16(af, bfr, acc[nt], 0, 0, 0);
        }
    }
    #pragma unroll
    for (int nt = 0; nt < 4; nt++) {
        int c = nt * 16 + r16;
        #pragma unroll
        for (int i = 0; i < 4; i++) {
            int rr = row0 + quad * 4 + i;
            if (rr < NN) {
                if (MODE == 0) {
                    ((ushort*)outv)[(size_t)rr * 64 + c] = f2bf(acc[nt][i]);
                } else {
                    union { ushort s; } ad; ad.s = addend[(size_t)rr * 64 + c];
                    union { uint i2; float f; } a2; a2.i2 = (uint)ad.s << 16;
                    ((float*)outv)[(size_t)rr * 64 + c] = acc[nt][i] + a2.f + bias[c];
                }
            }
        }
    }
}

// ---------- launch ----------
extern "C" void kernel_launch(void* const* d_in, const int* in_sizes, int n_in,
                              void* d_out, int out_size, void* d_ws, size_t ws_size,
                              hipStream_t stream) {
    const float* x   = (const float*)d_in[0];
    const int*   ei  = (const int*)d_in[1];
    const float* W1l = (const float*)d_in[2];
    const float* W1r = (const float*)d_in[3];
    const float* b1  = (const float*)d_in[4];
    const float* W2l = (const float*)d_in[5];
    const float* W2r = (const float*)d_in[6];
    const float* b2  = (const float*)d_in[7];
    float* out = (float*)d_out;

    const int* src = ei;
    const int* dst = ei + NE;

    char* w = (char*)d_ws;
    ushort* col  = (ushort*)w;                   w += (size_t)NN * BSTRIDE * 2;  // 9.6 MB
    int* cursor  = (int*)w;                      w += (size_t)NN * 4;            // 0.2 MB
    ushort* xb   = (ushort*)w;                   w += (size_t)NN * 128 * 2;      // 12.8 MB
    ushort* agg1 = (ushort*)w;                   w += (size_t)NN * 128 * 2;      // 12.8 MB
    ushort* h    = (ushort*)w;                   w += (size_t)NN * 128 * 2;      // 12.8 MB
    ushort* T1l  = (ushort*)w;                   w += 128 * 128 * 2;             // 32 KB
    ushort* T1r  = (ushort*)w;                   w += 128 * 128 * 2;             // 32 KB
    ushort* T2l  = (ushort*)w;                   w += 64 * 128 * 2;              // 16 KB
    ushort* T2r  = (ushort*)w;                   w += 64 * 128 * 2;              // 16 KB
    ushort* hW   = xb;                           // xb dead after k_agg128/gemm1
    ushort* agg2 = xb + (size_t)NN * 64;

    hipMemsetAsync(cursor, 0, (size_t)NN * 4, stream);
    k_cvt<<<NN * 128 / 4 / 256, 256, 0, stream>>>((const float4*)x, (ushort4*)xb);
    k_cvtW<<<192, 256, 0, stream>>>(W1l, W1r, W2l, W2r, T1l, T1r, T2l, T2r);
    k_fill<<<FILL_GRPS * 8, 256, 0, stream>>>(src, dst, cursor, col);

    k_agg128<<<NN / 4, 256, 0, stream>>>(xb, col, cursor, agg1);
    k_gemm1<<<(NN + 63) / 64, 256, 0, stream>>>(agg1, xb, T1l, T1r, b1, h);

    k_gemm2<0><<<(NN + 63) / 64, 256, 0, stream>>>(h, T2l, nullptr, nullptr, hW);
    k_agg64<<<NN / 4, 256, 0, stream>>>(hW, col, cursor, agg2);
    k_gemm2<1><<<(NN + 63) / 64, 256, 0, stream>>>(h, T2r, agg2, b2, out);
}

// Round 7
// 302.520 us; speedup vs baseline: 1.1603x; 1.0889x over previous
//
#include <hip/hip_runtime.h>

#define NN 50000
#define NE 1600000
#define BSTRIDE 96   // max degree slots; Poisson(32) tail at 96 is ~e^-41 per node
#define PARTN 6250   // NN / 8 XCDs
#define FILL_GRPS 512
#define FILL_CHUNK 3125  // NE / FILL_GRPS exactly
#define CURPAD 16    // one cursor counter per 64B line (d -> cursor[d<<4])

typedef __bf16 bf16x8 __attribute__((ext_vector_type(8)));
typedef float  f32x4  __attribute__((ext_vector_type(4)));

// ---------- bf16 helpers (RNE) ----------
__device__ __forceinline__ float bfLo(uint u) { union { uint i; float f; } v; v.i = u << 16; return v.f; }
__device__ __forceinline__ float bfHi(uint u) { union { uint i; float f; } v; v.i = u & 0xffff0000u; return v.f; }
__device__ __forceinline__ ushort f2bf(float f) {
    union { float f; uint i; } v; v.f = f;
    uint r = v.i + 0x7fffu + ((v.i >> 16) & 1u);
    return (ushort)(r >> 16);
}
__device__ __forceinline__ uint pack2(float a, float b) {
    return (uint)f2bf(a) | ((uint)f2bf(b) << 16);
}
__device__ __forceinline__ bf16x8 load8(const ushort* p) {
    union { uint4 u; bf16x8 b; } v; v.u = *(const uint4*)p; return v.b;
}

// ---------- prep: x->bf16 | weights fp32[K][N] -> bf16 T[N][K] | zero cursor ----------
// block ranges: [0,6250) x-convert, [6250,6442) weights, [6442,7224) cursor zero
__global__ void k_prep(const float4* __restrict__ x, ushort4* __restrict__ xb,
                       const float* __restrict__ W1l, const float* __restrict__ W1r,
                       const float* __restrict__ W2l, const float* __restrict__ W2r,
                       ushort* __restrict__ T1l, ushort* __restrict__ T1r,
                       ushort* __restrict__ T2l, ushort* __restrict__ T2r,
                       uint4* __restrict__ cursorv) {
    int b = blockIdx.x;
    if (b < 6250) {
        int i = b * 256 + threadIdx.x;            // NN*128/4 = 1.6M exactly
        float4 v = x[i];
        ushort4 o; o.x = f2bf(v.x); o.y = f2bf(v.y); o.z = f2bf(v.z); o.w = f2bf(v.w);
        xb[i] = o;
    } else if (b < 6442) {
        int i = (b - 6250) * 256 + threadIdx.x;   // 0 .. 49151
        if (i < 16384) {
            int k = i >> 7, n = i & 127; T1l[n * 128 + k] = f2bf(W1l[i]);
        } else if (i < 32768) {
            int j = i - 16384; int k = j >> 7, n = j & 127; T1r[n * 128 + k] = f2bf(W1r[j]);
        } else if (i < 40960) {
            int j = i - 32768; int k = j >> 6, n = j & 63;  T2l[n * 128 + k] = f2bf(W2l[j]);
        } else if (i < 49152) {
            int j = i - 40960; int k = j >> 6, n = j & 63;  T2r[n * 128 + k] = f2bf(W2r[j]);
        }
    } else {
        int i = (b - 6442) * 256 + threadIdx.x;   // NN*CURPAD/4 = 200000 uint4
        if (i < NN * CURPAD / 4) cursorv[i] = (uint4){0u, 0u, 0u, 0u};
    }
}

// ---------- bucketed CSR fill, XCD-partitioned by dst range, line-padded cursor ----------
__global__ __launch_bounds__(256) void k_fill(const int* __restrict__ src, const int* __restrict__ dst,
                       int* __restrict__ cursor, ushort* __restrict__ col) {
    const int xcd = blockIdx.x & 7;
    const int grp = blockIdx.x >> 3;           // 0..FILL_GRPS-1
    const int lo = xcd * PARTN;
    const int beg = grp * FILL_CHUNK;
    const int end = beg + FILL_CHUNK;
    #pragma unroll 4
    for (int i = beg + threadIdx.x; i < end; i += 256) {
        int d = dst[i];
        if ((unsigned)(d - lo) < (unsigned)PARTN) {
            int p = atomicAdd(&cursor[d << 4], 1);   // one counter per 64B line
            if (p < BSTRIDE) col[(size_t)d * BSTRIDE + p] = (ushort)src[i];
        }
    }
}

// ---------- aggregation, 128-dim bf16 rows ----------
// one wave per node; quarter-wave (16 lanes x 16B) covers one 256B neighbor row.
__global__ void k_agg128(const ushort* __restrict__ feat, const ushort* __restrict__ col,
                         const int* __restrict__ deg, ushort* __restrict__ out) {
    int node = (blockIdx.x * blockDim.x + threadIdx.x) >> 6;
    int lane = threadIdx.x & 63;
    int q = lane >> 4;         // neighbor slot within group of 4
    int c = lane & 15;         // dim group: dims c*8 .. c*8+7
    int d = deg[node << 4];
    int dd = min(d, BSTRIDE);
    const ushort* cb = col + (size_t)node * BSTRIDE;
    float a0=0.f,a1=0.f,a2=0.f,a3=0.f,a4=0.f,a5=0.f,a6=0.f,a7=0.f;
    for (int j0 = 0; j0 < dd; j0 += 64) {
        int idx = (j0 + lane < dd) ? (int)cb[j0 + lane] : 0;
        int cnt = min(64, dd - j0);
        for (int t = 0; t < cnt; t += 4) {
            int s = __shfl(idx, t + q);
            if (t + q < cnt) {
                uint4 u = *(const uint4*)(feat + (size_t)s * 128 + c * 8);
                a0 += bfLo(u.x); a1 += bfHi(u.x);
                a2 += bfLo(u.y); a3 += bfHi(u.y);
                a4 += bfLo(u.z); a5 += bfHi(u.z);
                a6 += bfLo(u.w); a7 += bfHi(u.w);
            }
        }
    }
    a0 += __shfl_xor(a0, 16); a0 += __shfl_xor(a0, 32);
    a1 += __shfl_xor(a1, 16); a1 += __shfl_xor(a1, 32);
    a2 += __shfl_xor(a2, 16); a2 += __shfl_xor(a2, 32);
    a3 += __shfl_xor(a3, 16); a3 += __shfl_xor(a3, 32);
    a4 += __shfl_xor(a4, 16); a4 += __shfl_xor(a4, 32);
    a5 += __shfl_xor(a5, 16); a5 += __shfl_xor(a5, 32);
    a6 += __shfl_xor(a6, 16); a6 += __shfl_xor(a6, 32);
    a7 += __shfl_xor(a7, 16); a7 += __shfl_xor(a7, 32);
    if (q == 0) {
        float inv = 1.f / fmaxf((float)d, 1.f);
        uint4 o;
        o.x = pack2(a0 * inv, a1 * inv);
        o.y = pack2(a2 * inv, a3 * inv);
        o.z = pack2(a4 * inv, a5 * inv);
        o.w = pack2(a6 * inv, a7 * inv);
        *(uint4*)(out + (size_t)node * 128 + c * 8) = o;
    }
}

// ---------- aggregation, 64-dim bf16 rows ----------
__global__ void k_agg64(const ushort* __restrict__ feat, const ushort* __restrict__ col,
                        const int* __restrict__ deg, ushort* __restrict__ out) {
    int node = (blockIdx.x * blockDim.x + threadIdx.x) >> 6;
    int lane = threadIdx.x & 63;
    int q = lane >> 3;         // neighbor slot within group of 8
    int c = lane & 7;          // dim group: dims c*8 .. c*8+7
    int d = deg[node << 4];
    int dd = min(d, BSTRIDE);
    const ushort* cb = col + (size_t)node * BSTRIDE;
    float a0=0.f,a1=0.f,a2=0.f,a3=0.f,a4=0.f,a5=0.f,a6=0.f,a7=0.f;
    for (int j0 = 0; j0 < dd; j0 += 64) {
        int idx = (j0 + lane < dd) ? (int)cb[j0 + lane] : 0;
        int cnt = min(64, dd - j0);
        for (int t = 0; t < cnt; t += 8) {
            int s = __shfl(idx, t + q);
            if (t + q < cnt) {
                uint4 u = *(const uint4*)(feat + (size_t)s * 64 + c * 8);
                a0 += bfLo(u.x); a1 += bfHi(u.x);
                a2 += bfLo(u.y); a3 += bfHi(u.y);
                a4 += bfLo(u.z); a5 += bfHi(u.z);
                a6 += bfLo(u.w); a7 += bfHi(u.w);
            }
        }
    }
    #pragma unroll
    for (int m = 8; m < 64; m <<= 1) {
        a0 += __shfl_xor(a0, m); a1 += __shfl_xor(a1, m);
        a2 += __shfl_xor(a2, m); a3 += __shfl_xor(a3, m);
        a4 += __shfl_xor(a4, m); a5 += __shfl_xor(a5, m);
        a6 += __shfl_xor(a6, m); a7 += __shfl_xor(a7, m);
    }
    if (q == 0) {
        float inv = 1.f / fmaxf((float)d, 1.f);
        uint4 o;
        o.x = pack2(a0 * inv, a1 * inv);
        o.y = pack2(a2 * inv, a3 * inv);
        o.z = pack2(a4 * inv, a5 * inv);
        o.w = pack2(a6 * inv, a7 * inv);
        *(uint4*)(out + (size_t)node * 64 + c * 8) = o;
    }
}

// ---------- MFMA GEMM 1: h = relu(agg1@W1l + xb@W1r + b1) ----------
__global__ __launch_bounds__(256) void k_gemm1(
    const ushort* __restrict__ agg, const ushort* __restrict__ xb,
    const ushort* __restrict__ T1l, const ushort* __restrict__ T1r,
    const float* __restrict__ bias, ushort* __restrict__ out) {
    const int lane = threadIdx.x & 63;
    const int quad = lane >> 4, r16 = lane & 15;
    const int row0 = blockIdx.x * 64 + (threadIdx.x >> 6) * 16;
    const int arow = min(row0 + r16, NN - 1);
    f32x4 acc[8];
    #pragma unroll
    for (int nt = 0; nt < 8; nt++) acc[nt] = (f32x4){0.f, 0.f, 0.f, 0.f};

    #pragma unroll
    for (int seg = 0; seg < 2; seg++) {
        const ushort* A  = seg ? xb  : agg;
        const ushort* WT = seg ? T1r : T1l;
        #pragma unroll
        for (int kt = 0; kt < 4; kt++) {
            const int k = kt * 32 + quad * 8;
            bf16x8 af = load8(A + (size_t)arow * 128 + k);
            #pragma unroll
            for (int nt = 0; nt < 8; nt++) {
                bf16x8 bfr = load8(WT + (nt * 16 + r16) * 128 + k);
                acc[nt] = __builtin_amdgcn_mfma_f32_16x16x32_bf16(af, bfr, acc[nt], 0, 0, 0);
            }
        }
    }
    #pragma unroll
    for (int nt = 0; nt < 8; nt++) {
        int c = nt * 16 + r16;
        float bv = bias[c];
        #pragma unroll
        for (int i = 0; i < 4; i++) {
            int rr = row0 + quad * 4 + i;
            if (rr < NN) out[(size_t)rr * 128 + c] = f2bf(fmaxf(acc[nt][i] + bv, 0.f));
        }
    }
}

// ---------- MFMA GEMM 2: A[N,128]bf16 @ WT[64][128] ; MODE 0 -> bf16, MODE 1 -> +agg2+bias fp32 ----------
template <int MODE>
__global__ __launch_bounds__(256) void k_gemm2(
    const ushort* __restrict__ A, const ushort* __restrict__ WT,
    const ushort* __restrict__ addend, const float* __restrict__ bias,
    void* __restrict__ outv) {
    const int lane = threadIdx.x & 63;
    const int quad = lane >> 4, r16 = lane & 15;
    const int row0 = blockIdx.x * 64 + (threadIdx.x >> 6) * 16;
    const int arow = min(row0 + r16, NN - 1);
    f32x4 acc[4];
    #pragma unroll
    for (int nt = 0; nt < 4; nt++) acc[nt] = (f32x4){0.f, 0.f, 0.f, 0.f};

    #pragma unroll
    for (int kt = 0; kt < 4; kt++) {
        const int k = kt * 32 + quad * 8;
        bf16x8 af = load8(A + (size_t)arow * 128 + k);
        #pragma unroll
        for (int nt = 0; nt < 4; nt++) {
            bf16x8 bfr = load8(WT + (nt * 16 + r16) * 128 + k);
            acc[nt] = __builtin_amdgcn_mfma_f32_16x16x32_bf16(af, bfr, acc[nt], 0, 0, 0);
        }
    }
    #pragma unroll
    for (int nt = 0; nt < 4; nt++) {
        int c = nt * 16 + r16;
        #pragma unroll
        for (int i = 0; i < 4; i++) {
            int rr = row0 + quad * 4 + i;
            if (rr < NN) {
                if (MODE == 0) {
                    ((ushort*)outv)[(size_t)rr * 64 + c] = f2bf(acc[nt][i]);
                } else {
                    union { uint i2; float f; } a2; a2.i2 = (uint)addend[(size_t)rr * 64 + c] << 16;
                    ((float*)outv)[(size_t)rr * 64 + c] = acc[nt][i] + a2.f + bias[c];
                }
            }
        }
    }
}

// ---------- launch ----------
extern "C" void kernel_launch(void* const* d_in, const int* in_sizes, int n_in,
                              void* d_out, int out_size, void* d_ws, size_t ws_size,
                              hipStream_t stream) {
    const float* x   = (const float*)d_in[0];
    const int*   ei  = (const int*)d_in[1];
    const float* W1l = (const float*)d_in[2];
    const float* W1r = (const float*)d_in[3];
    const float* b1  = (const float*)d_in[4];
    const float* W2l = (const float*)d_in[5];
    const float* W2r = (const float*)d_in[6];
    const float* b2  = (const float*)d_in[7];
    float* out = (float*)d_out;

    const int* src = ei;
    const int* dst = ei + NE;

    char* w = (char*)d_ws;
    ushort* col  = (ushort*)w;                   w += (size_t)NN * BSTRIDE * 2;   // 9.6 MB
    int* cursor  = (int*)w;                      w += (size_t)NN * CURPAD * 4;    // 3.2 MB
    ushort* xb   = (ushort*)w;                   w += (size_t)NN * 128 * 2;       // 12.8 MB
    ushort* agg1 = (ushort*)w;                   w += (size_t)NN * 128 * 2;       // 12.8 MB
    ushort* h    = (ushort*)w;                   w += (size_t)NN * 128 * 2;       // 12.8 MB
    ushort* T1l  = (ushort*)w;                   w += 128 * 128 * 2;              // 32 KB
    ushort* T1r  = (ushort*)w;                   w += 128 * 128 * 2;              // 32 KB
    ushort* T2l  = (ushort*)w;                   w += 64 * 128 * 2;               // 16 KB
    ushort* T2r  = (ushort*)w;                   w += 64 * 128 * 2;               // 16 KB
    ushort* hW   = xb;                           // xb dead after k_agg128/gemm1
    ushort* agg2 = xb + (size_t)NN * 64;

    k_prep<<<7224, 256, 0, stream>>>((const float4*)x, (ushort4*)xb,
                                     W1l, W1r, W2l, W2r, T1l, T1r, T2l, T2r,
                                     (uint4*)cursor);
    k_fill<<<FILL_GRPS * 8, 256, 0, stream>>>(src, dst, cursor, col);

    k_agg128<<<NN / 4, 256, 0, stream>>>(xb, col, cursor, agg1);
    k_gemm1<<<(NN + 63) / 64, 256, 0, stream>>>(agg1, xb, T1l, T1r, b1, h);

    k_gemm2<0><<<(NN + 63) / 64, 256, 0, stream>>>(h, T2l, nullptr, nullptr, hW);
    k_agg64<<<NN / 4, 256, 0, stream>>>(hW, col, cursor, agg2);
    k_gemm2<1><<<(NN + 63) / 64, 256, 0, stream>>>(h, T2r, agg2, b2, out);
}

// Round 8
// 262.922 us; speedup vs baseline: 1.3351x; 1.1506x over previous
//
#include <hip/hip_runtime.h>

#define NN 50000
#define NE 1600000
#define BSTRIDE 96   // max degree slots; Poisson(32) tail at 96 is ~e^-41 per node
#define C_BKT 196    // dst buckets of 256 nodes: ceil(50000/256)
#define P1_BLKS 512
#define P1_CHUNK 3125 // NE / P1_BLKS exactly
#define CAP 56       // per-(block,bucket) cell capacity; Poisson(16) P(>=56) ~ 1e-14

typedef __bf16 bf16x8 __attribute__((ext_vector_type(8)));
typedef float  f32x4  __attribute__((ext_vector_type(4)));

// ---------- bf16 helpers (RNE) ----------
__device__ __forceinline__ float bfLo(uint u) { union { uint i; float f; } v; v.i = u << 16; return v.f; }
__device__ __forceinline__ float bfHi(uint u) { union { uint i; float f; } v; v.i = u & 0xffff0000u; return v.f; }
__device__ __forceinline__ ushort f2bf(float f) {
    union { float f; uint i; } v; v.f = f;
    uint r = v.i + 0x7fffu + ((v.i >> 16) & 1u);
    return (ushort)(r >> 16);
}
__device__ __forceinline__ uint pack2(float a, float b) {
    return (uint)f2bf(a) | ((uint)f2bf(b) << 16);
}
__device__ __forceinline__ bf16x8 load8(const ushort* p) {
    union { uint4 u; bf16x8 b; } v; v.u = *(const uint4*)p; return v.b;
}

// ---------- prep: x->bf16 | weights fp32[K][N] -> bf16 T[N][K] ----------
__global__ void k_prep(const float4* __restrict__ x, ushort4* __restrict__ xb,
                       const float* __restrict__ W1l, const float* __restrict__ W1r,
                       const float* __restrict__ W2l, const float* __restrict__ W2r,
                       ushort* __restrict__ T1l, ushort* __restrict__ T1r,
                       ushort* __restrict__ T2l, ushort* __restrict__ T2r) {
    int b = blockIdx.x;
    if (b < 6250) {
        int i = b * 256 + threadIdx.x;            // NN*128/4 = 1.6M exactly
        float4 v = x[i];
        ushort4 o; o.x = f2bf(v.x); o.y = f2bf(v.y); o.z = f2bf(v.z); o.w = f2bf(v.w);
        xb[i] = o;
    } else {
        int i = (b - 6250) * 256 + threadIdx.x;   // 0 .. 49151
        if (i < 16384) {
            int k = i >> 7, n = i & 127; T1l[n * 128 + k] = f2bf(W1l[i]);
        } else if (i < 32768) {
            int j = i - 16384; int k = j >> 7, n = j & 127; T1r[n * 128 + k] = f2bf(W1r[j]);
        } else if (i < 40960) {
            int j = i - 32768; int k = j >> 6, n = j & 63;  T2l[n * 128 + k] = f2bf(W2l[j]);
        } else if (i < 49152) {
            int j = i - 40960; int k = j >> 6, n = j & 63;  T2r[n * 128 + k] = f2bf(W2r[j]);
        }
    }
}

// ---------- CSR build pass 1: radix-partition edges into (block,bucket) cells ----------
// No global atomics: per-block LDS histogram gives the cell slot; cells are
// block-private (single writer, L2-local). entry = (d&255)<<16 | src.
__global__ __launch_bounds__(256) void k_part1(const int* __restrict__ src, const int* __restrict__ dst,
                        uint* __restrict__ cells, ushort* __restrict__ cnt) {
    __shared__ uint hist[C_BKT];
    for (int i = threadIdx.x; i < C_BKT; i += 256) hist[i] = 0;
    __syncthreads();
    const int b = blockIdx.x;
    const int beg = b * P1_CHUNK;
    uint* myCells = cells + (size_t)b * C_BKT * CAP;
    #pragma unroll 4
    for (int i = beg + threadIdx.x; i < beg + P1_CHUNK; i += 256) {
        int d = dst[i];
        int s = src[i];
        int c = d >> 8;
        uint p = atomicAdd(&hist[c], 1);   // LDS atomic
        if (p < CAP) myCells[c * CAP + p] = ((uint)(d & 255) << 16) | (uint)s;
    }
    __syncthreads();
    for (int i = threadIdx.x; i < C_BKT; i += 256)
        cnt[(size_t)b * C_BKT + i] = (ushort)min(hist[i], (uint)CAP);
}

// ---------- CSR build pass 2: per-bucket gather, final slots via LDS atomics ----------
// block c owns nodes [c*256, c*256+256); writes its private col slice and deg[]
// directly (no global cursor at all). 1024 threads: 2 threads per P1-block cell.
__global__ __launch_bounds__(1024) void k_part2(const uint* __restrict__ cells,
                        const ushort* __restrict__ cnt,
                        ushort* __restrict__ col, int* __restrict__ deg) {
    __shared__ uint hist[256];
    const int c = blockIdx.x;
    if (threadIdx.x < 256) hist[threadIdx.x] = 0;
    __syncthreads();
    const int b = threadIdx.x >> 1;            // 0..511
    const int sub = threadIdx.x & 1;
    const uint* cell = cells + ((size_t)b * C_BKT + c) * CAP;
    const int n = cnt[(size_t)b * C_BKT + c];
    const int nodeBase = c << 8;
    for (int j = sub; j < n; j += 2) {
        uint e = cell[j];
        int dl = e >> 16;
        uint p = atomicAdd(&hist[dl], 1);      // LDS atomic
        if (p < BSTRIDE)
            col[(size_t)(nodeBase + dl) * BSTRIDE + p] = (ushort)(e & 0xFFFF);
    }
    __syncthreads();
    if (threadIdx.x < 256) {
        int node = nodeBase + threadIdx.x;
        if (node < NN) deg[node] = (int)hist[threadIdx.x];
    }
}

// ---------- aggregation, 128-dim bf16 rows ----------
// one wave per node; quarter-wave (16 lanes x 16B) covers one 256B neighbor row.
__global__ void k_agg128(const ushort* __restrict__ feat, const ushort* __restrict__ col,
                         const int* __restrict__ deg, ushort* __restrict__ out) {
    int node = (blockIdx.x * blockDim.x + threadIdx.x) >> 6;
    int lane = threadIdx.x & 63;
    int q = lane >> 4;         // neighbor slot within group of 4
    int c = lane & 15;         // dim group: dims c*8 .. c*8+7
    int d = deg[node];
    int dd = min(d, BSTRIDE);
    const ushort* cb = col + (size_t)node * BSTRIDE;
    float a0=0.f,a1=0.f,a2=0.f,a3=0.f,a4=0.f,a5=0.f,a6=0.f,a7=0.f;
    for (int j0 = 0; j0 < dd; j0 += 64) {
        int idx = (j0 + lane < dd) ? (int)cb[j0 + lane] : 0;
        int cnt = min(64, dd - j0);
        for (int t = 0; t < cnt; t += 4) {
            int s = __shfl(idx, t + q);
            if (t + q < cnt) {
                uint4 u = *(const uint4*)(feat + (size_t)s * 128 + c * 8);
                a0 += bfLo(u.x); a1 += bfHi(u.x);
                a2 += bfLo(u.y); a3 += bfHi(u.y);
                a4 += bfLo(u.z); a5 += bfHi(u.z);
                a6 += bfLo(u.w); a7 += bfHi(u.w);
            }
        }
    }
    a0 += __shfl_xor(a0, 16); a0 += __shfl_xor(a0, 32);
    a1 += __shfl_xor(a1, 16); a1 += __shfl_xor(a1, 32);
    a2 += __shfl_xor(a2, 16); a2 += __shfl_xor(a2, 32);
    a3 += __shfl_xor(a3, 16); a3 += __shfl_xor(a3, 32);
    a4 += __shfl_xor(a4, 16); a4 += __shfl_xor(a4, 32);
    a5 += __shfl_xor(a5, 16); a5 += __shfl_xor(a5, 32);
    a6 += __shfl_xor(a6, 16); a6 += __shfl_xor(a6, 32);
    a7 += __shfl_xor(a7, 16); a7 += __shfl_xor(a7, 32);
    if (q == 0) {
        float inv = 1.f / fmaxf((float)d, 1.f);
        uint4 o;
        o.x = pack2(a0 * inv, a1 * inv);
        o.y = pack2(a2 * inv, a3 * inv);
        o.z = pack2(a4 * inv, a5 * inv);
        o.w = pack2(a6 * inv, a7 * inv);
        *(uint4*)(out + (size_t)node * 128 + c * 8) = o;
    }
}

// ---------- aggregation, 64-dim bf16 rows ----------
__global__ void k_agg64(const ushort* __restrict__ feat, const ushort* __restrict__ col,
                        const int* __restrict__ deg, ushort* __restrict__ out) {
    int node = (blockIdx.x * blockDim.x + threadIdx.x) >> 6;
    int lane = threadIdx.x & 63;
    int q = lane >> 3;         // neighbor slot within group of 8
    int c = lane & 7;          // dim group: dims c*8 .. c*8+7
    int d = deg[node];
    int dd = min(d, BSTRIDE);
    const ushort* cb = col + (size_t)node * BSTRIDE;
    float a0=0.f,a1=0.f,a2=0.f,a3=0.f,a4=0.f,a5=0.f,a6=0.f,a7=0.f;
    for (int j0 = 0; j0 < dd; j0 += 64) {
        int idx = (j0 + lane < dd) ? (int)cb[j0 + lane] : 0;
        int cnt = min(64, dd - j0);
        for (int t = 0; t < cnt; t += 8) {
            int s = __shfl(idx, t + q);
            if (t + q < cnt) {
                uint4 u = *(const uint4*)(feat + (size_t)s * 64 + c * 8);
                a0 += bfLo(u.x); a1 += bfHi(u.x);
                a2 += bfLo(u.y); a3 += bfHi(u.y);
                a4 += bfLo(u.z); a5 += bfHi(u.z);
                a6 += bfLo(u.w); a7 += bfHi(u.w);
            }
        }
    }
    #pragma unroll
    for (int m = 8; m < 64; m <<= 1) {
        a0 += __shfl_xor(a0, m); a1 += __shfl_xor(a1, m);
        a2 += __shfl_xor(a2, m); a3 += __shfl_xor(a3, m);
        a4 += __shfl_xor(a4, m); a5 += __shfl_xor(a5, m);
        a6 += __shfl_xor(a6, m); a7 += __shfl_xor(a7, m);
    }
    if (q == 0) {
        float inv = 1.f / fmaxf((float)d, 1.f);
        uint4 o;
        o.x = pack2(a0 * inv, a1 * inv);
        o.y = pack2(a2 * inv, a3 * inv);
        o.z = pack2(a4 * inv, a5 * inv);
        o.w = pack2(a6 * inv, a7 * inv);
        *(uint4*)(out + (size_t)node * 64 + c * 8) = o;
    }
}

// ---------- MFMA GEMM 1: h = relu(agg1@W1l + xb@W1r + b1) ----------
__global__ __launch_bounds__(256) void k_gemm1(
    const ushort* __restrict__ agg, const ushort* __restrict__ xb,
    const ushort* __restrict__ T1l, const ushort* __restrict__ T1r,
    const float* __restrict__ bias, ushort* __restrict__ out) {
    const int lane = threadIdx.x & 63;
    const int quad = lane >> 4, r16 = lane & 15;
    const int row0 = blockIdx.x * 64 + (threadIdx.x >> 6) * 16;
    const int arow = min(row0 + r16, NN - 1);
    f32x4 acc[8];
    #pragma unroll
    for (int nt = 0; nt < 8; nt++) acc[nt] = (f32x4){0.f, 0.f, 0.f, 0.f};

    #pragma unroll
    for (int seg = 0; seg < 2; seg++) {
        const ushort* A  = seg ? xb  : agg;
        const ushort* WT = seg ? T1r : T1l;
        #pragma unroll
        for (int kt = 0; kt < 4; kt++) {
            const int k = kt * 32 + quad * 8;
            bf16x8 af = load8(A + (size_t)arow * 128 + k);
            #pragma unroll
            for (int nt = 0; nt < 8; nt++) {
                bf16x8 bfr = load8(WT + (nt * 16 + r16) * 128 + k);
                acc[nt] = __builtin_amdgcn_mfma_f32_16x16x32_bf16(af, bfr, acc[nt], 0, 0, 0);
            }
        }
    }
    #pragma unroll
    for (int nt = 0; nt < 8; nt++) {
        int c = nt * 16 + r16;
        float bv = bias[c];
        #pragma unroll
        for (int i = 0; i < 4; i++) {
            int rr = row0 + quad * 4 + i;
            if (rr < NN) out[(size_t)rr * 128 + c] = f2bf(fmaxf(acc[nt][i] + bv, 0.f));
        }
    }
}

// ---------- MFMA GEMM 2: A[N,128]bf16 @ WT[64][128] ; MODE 0 -> bf16, MODE 1 -> +agg2+bias fp32 ----------
template <int MODE>
__global__ __launch_bounds__(256) void k_gemm2(
    const ushort* __restrict__ A, const ushort* __restrict__ WT,
    const ushort* __restrict__ addend, const float* __restrict__ bias,
    void* __restrict__ outv) {
    const int lane = threadIdx.x & 63;
    const int quad = lane >> 4, r16 = lane & 15;
    const int row0 = blockIdx.x * 64 + (threadIdx.x >> 6) * 16;
    const int arow = min(row0 + r16, NN - 1);
    f32x4 acc[4];
    #pragma unroll
    for (int nt = 0; nt < 4; nt++) acc[nt] = (f32x4){0.f, 0.f, 0.f, 0.f};

    #pragma unroll
    for (int kt = 0; kt < 4; kt++) {
        const int k = kt * 32 + quad * 8;
        bf16x8 af = load8(A + (size_t)arow * 128 + k);
        #pragma unroll
        for (int nt = 0; nt < 4; nt++) {
            bf16x8 bfr = load8(WT + (nt * 16 + r16) * 128 + k);
            acc[nt] = __builtin_amdgcn_mfma_f32_16x16x32_bf16(af, bfr, acc[nt], 0, 0, 0);
        }
    }
    #pragma unroll
    for (int nt = 0; nt < 4; nt++) {
        int c = nt * 16 + r16;
        #pragma unroll
        for (int i = 0; i < 4; i++) {
            int rr = row0 + quad * 4 + i;
            if (rr < NN) {
                if (MODE == 0) {
                    ((ushort*)outv)[(size_t)rr * 64 + c] = f2bf(acc[nt][i]);
                } else {
                    union { uint i2; float f; } a2; a2.i2 = (uint)addend[(size_t)rr * 64 + c] << 16;
                    ((float*)outv)[(size_t)rr * 64 + c] = acc[nt][i] + a2.f + bias[c];
                }
            }
        }
    }
}

// ---------- launch ----------
extern "C" void kernel_launch(void* const* d_in, const int* in_sizes, int n_in,
                              void* d_out, int out_size, void* d_ws, size_t ws_size,
                              hipStream_t stream) {
    const float* x   = (const float*)d_in[0];
    const int*   ei  = (const int*)d_in[1];
    const float* W1l = (const float*)d_in[2];
    const float* W1r = (const float*)d_in[3];
    const float* b1  = (const float*)d_in[4];
    const float* W2l = (const float*)d_in[5];
    const float* W2r = (const float*)d_in[6];
    const float* b2  = (const float*)d_in[7];
    float* out = (float*)d_out;

    const int* src = ei;
    const int* dst = ei + NE;

    char* w = (char*)d_ws;
    ushort* col  = (ushort*)w;                   w += (size_t)NN * BSTRIDE * 2;      // 9.6 MB
    int* deg     = (int*)w;                      w += (size_t)50048 * 4;             // 0.2 MB
    ushort* cnt  = (ushort*)w;                   w += (size_t)P1_BLKS * C_BKT * 2;   // 0.2 MB
    ushort* xb   = (ushort*)w;                   w += (size_t)NN * 128 * 2;          // 12.8 MB
    ushort* T1l  = (ushort*)w;                   w += 128 * 128 * 2;                 // 32 KB
    ushort* T1r  = (ushort*)w;                   w += 128 * 128 * 2;                 // 32 KB
    ushort* T2l  = (ushort*)w;                   w += 64 * 128 * 2;                  // 16 KB
    ushort* T2r  = (ushort*)w;                   w += 64 * 128 * 2;                  // 16 KB
    ushort* agg1 = (ushort*)w;                   w += (size_t)NN * 128 * 2;          // 12.8 MB
    ushort* h    = (ushort*)w;                   w += (size_t)NN * 128 * 2;          // 12.8 MB
    uint* cells  = (uint*)agg1;                  // 22.5 MB, aliases agg1+h (dead after k_part2)
    ushort* hW   = xb;                           // xb dead after k_agg128/gemm1
    ushort* agg2 = xb + (size_t)NN * 64;

    k_prep<<<6442, 256, 0, stream>>>((const float4*)x, (ushort4*)xb,
                                     W1l, W1r, W2l, W2r, T1l, T1r, T2l, T2r);
    k_part1<<<P1_BLKS, 256, 0, stream>>>(src, dst, cells, cnt);
    k_part2<<<C_BKT, 1024, 0, stream>>>(cells, cnt, col, deg);

    k_agg128<<<NN / 4, 256, 0, stream>>>(xb, col, deg, agg1);
    k_gemm1<<<(NN + 63) / 64, 256, 0, stream>>>(agg1, xb, T1l, T1r, b1, h);

    k_gemm2<0><<<(NN + 63) / 64, 256, 0, stream>>>(h, T2l, nullptr, nullptr, hW);
    k_agg64<<<NN / 4, 256, 0, stream>>>(hW, col, deg, agg2);
    k_gemm2<1><<<(NN + 63) / 64, 256, 0, stream>>>(h, T2r, agg2, b2, out);
}